// Round 2
// baseline (1545.105 us; speedup 1.0000x reference)
//
#include <hip/hip_runtime.h>
#include <hip/hip_bf16.h>
#include <stdint.h>

// Problem constants
#define BATCH 8
#define NPTS  4096
#define CIN   64
#define MPTS  1024
#define KNN   32
#define CCOV  64
#define COUT  128

typedef unsigned long long u64;

// ---------------------------------------------------------------------------
// K0: transpose f [B, 64, 4096] -> fT [B, 4096, 64] for coalesced gathers
// ---------------------------------------------------------------------------
__global__ void k_transpose(const float* __restrict__ f, float* __restrict__ fT) {
    __shared__ float tile[64][65];
    int b  = blockIdx.y;
    int n0 = blockIdx.x * 64;
    int tx = threadIdx.x & 63;
    int ty = threadIdx.x >> 6;   // 0..3
#pragma unroll
    for (int r = 0; r < 16; ++r) {
        int c = r * 4 + ty;
        tile[c][tx] = f[((size_t)b * CIN + c) * NPTS + n0 + tx];
    }
    __syncthreads();
#pragma unroll
    for (int r = 0; r < 16; ++r) {
        int n = r * 4 + ty;
        fT[((size_t)b * NPTS + n0 + n) * CIN + tx] = tile[tx][n];
    }
}

// ---------------------------------------------------------------------------
// K1: farthest point sampling, FLOAT64 distance math to bit-match the np-f64
// reference's selections. One block (1024 threads) per batch, 4 pts/thread.
// Argmax key: u64 = (f64 dist bits with low 12 mantissa bits masked) | (~idx
// & 0xFFF), max-reduced -> max dist, first-index tie-break (ties below
// 2^-40 relative are measure-zero for random data).
// ---------------------------------------------------------------------------
__launch_bounds__(1024, 1)
__global__ void k_fps(const float* __restrict__ xyz, float* __restrict__ xyz_new) {
    __shared__ float sx[NPTS], sy[NPTS], sz[NPTS];
    __shared__ u64 red[32];          // 16 slots x 2 parity
    int b   = blockIdx.x;
    int tid = threadIdx.x;
    const float* xb = xyz + (size_t)b * NPTS * 3;
    double px[4], py[4], pz[4], dist[4];
#pragma unroll
    for (int j = 0; j < 4; ++j) {
        int i = tid + 1024 * j;
        float x = xb[i * 3 + 0], y = xb[i * 3 + 1], z = xb[i * 3 + 2];
        sx[i] = x; sy[i] = y; sz[i] = z;
        px[j] = (double)x; py[j] = (double)y; pz[j] = (double)z;
        dist[j] = 1e10;
    }
    __syncthreads();

    int lane = tid & 63, wid = tid >> 6;
    int far = 0;
    float* xout = xyz_new + (size_t)b * MPTS * 3;

    for (int m = 0; m < MPTS; ++m) {
        float fxs = sx[far], fys = sy[far], fzs = sz[far];
        if (tid == 0) {   // record centroid BEFORE update (scan semantics)
            xout[m * 3 + 0] = fxs;
            xout[m * 3 + 1] = fys;
            xout[m * 3 + 2] = fzs;
        }
        double fx = (double)fxs, fy = (double)fys, fz = (double)fzs;
        u64 bk = 0;
#pragma unroll
        for (int j = 0; j < 4; ++j) {
            double dx = __dsub_rn(px[j], fx);
            double dy = __dsub_rn(py[j], fy);
            double dz = __dsub_rn(pz[j], fz);
            double d  = __dadd_rn(__dadd_rn(__dmul_rn(dx, dx), __dmul_rn(dy, dy)),
                                  __dmul_rn(dz, dz));
            dist[j] = fmin(dist[j], d);
            u64 k = ((u64)__double_as_longlong(dist[j]) & ~0xFFFull) |
                    (u64)((~(unsigned int)(tid + 1024 * j)) & 0xFFFu);
            if (k > bk) bk = k;
        }
        // wave reduce (max key)
#pragma unroll
        for (int off = 32; off; off >>= 1) {
            u64 ok = __shfl_down(bk, off);
            if (ok > bk) bk = ok;
        }
        int base = (m & 1) << 4;
        if (lane == 0) red[base + wid] = bk;
        __syncthreads();
        u64 gk = red[base + 0];
#pragma unroll
        for (int w = 1; w < 16; ++w) {
            u64 o = red[base + w];
            if (o > gk) gk = o;
        }
        far = (int)((~(unsigned int)gk) & 0xFFFu);
    }
}

// ---------------------------------------------------------------------------
// K2: per-query (one wave) brute-force 32-NN (f64 distance ordering) +
//     feature max-pool + covariance + mlp_cov. Writes f_cat [B*M,128].
// Keys: u64 = (f64 d2 bits, low 12 mantissa bits replaced by point idx).
// Unique keys -> iterative min-extraction with "key >= last+1" filter, no
// removal mask, registers only (all indices compile-time).
// ---------------------------------------------------------------------------
__launch_bounds__(64)
__global__ void k_knn(const float* __restrict__ xyz, const float* __restrict__ xyz_new,
                      const float* __restrict__ fT, const float* __restrict__ Wcov,
                      const float* __restrict__ bcov, float* __restrict__ fcat) {
    int q = blockIdx.x;            // 0..8191
    int b = q >> 10, m = q & 1023;
    int lane = threadIdx.x;
    const float* xb = xyz + (size_t)b * NPTS * 3;

    double cx = (double)xyz_new[((size_t)b * MPTS + m) * 3 + 0];
    double cy = (double)xyz_new[((size_t)b * MPTS + m) * 3 + 1];
    double cz = (double)xyz_new[((size_t)b * MPTS + m) * 3 + 2];

    u64 key[64];
#pragma unroll
    for (int t = 0; t < 64; ++t) {
        int i = lane + 64 * t;
        double dx = __dsub_rn(cx, (double)xb[i * 3 + 0]);
        double dy = __dsub_rn(cy, (double)xb[i * 3 + 1]);
        double dz = __dsub_rn(cz, (double)xb[i * 3 + 2]);
        double d2 = __dadd_rn(__dadd_rn(__dmul_rn(dx, dx), __dmul_rn(dy, dy)),
                              __dmul_rn(dz, dz));
        key[t] = ((u64)__double_as_longlong(d2) & ~0xFFFull) | (u64)i;
    }

    __shared__ int sknn[KNN];
    u64 thr = 0;
    for (int it = 0; it < KNN; ++it) {
        u64 best = ~0ull;
#pragma unroll
        for (int t = 0; t < 64; ++t) {
            u64 v = key[t];
            if (v >= thr && v < best) best = v;
        }
#pragma unroll
        for (int off = 1; off < 64; off <<= 1) {
            u64 o = __shfl_xor(best, off);
            if (o < best) best = o;
        }
        if (lane == 0) sknn[it] = (int)(best & 0xFFFull);
        thr = best + 1;
    }
    __syncthreads();

    // --- covariance of neighbor coords (each neighbor counted twice: /64) ---
    int nk = sknn[lane & 31];
    float nx = xb[nk * 3 + 0], ny = xb[nk * 3 + 1], nz = xb[nk * 3 + 2];
    float sxs = nx, sys = ny, szs = nz;
#pragma unroll
    for (int off = 1; off < 64; off <<= 1) {
        sxs += __shfl_xor(sxs, off);
        sys += __shfl_xor(sys, off);
        szs += __shfl_xor(szs, off);
    }
    float mx = sxs * (1.f / 64.f), my = sys * (1.f / 64.f), mz = szs * (1.f / 64.f);
    float ux = nx - mx, uy = ny - my, uz = nz - mz;
    float pxx = ux * ux, pxy = ux * uy, pxz = ux * uz;
    float pyy = uy * uy, pyz = uy * uz, pzz = uz * uz;
#pragma unroll
    for (int off = 1; off < 64; off <<= 1) {
        pxx += __shfl_xor(pxx, off);
        pxy += __shfl_xor(pxy, off);
        pxz += __shfl_xor(pxz, off);
        pyy += __shfl_xor(pyy, off);
        pyz += __shfl_xor(pyz, off);
        pzz += __shfl_xor(pzz, off);
    }
    const float inv = 1.f / 64.f;   // = (sum*2)/(2*K), K=32
    float c9[9];
    c9[0] = pxx * inv; c9[1] = pxy * inv; c9[2] = pxz * inv;
    c9[3] = pxy * inv; c9[4] = pyy * inv; c9[5] = pyz * inv;
    c9[6] = pxz * inv; c9[7] = pyz * inv; c9[8] = pzz * inv;

    // --- mlp_cov: lane = out channel c of 64 ---
    float acc = bcov[lane];
#pragma unroll
    for (int j = 0; j < 9; ++j) acc = fmaf(Wcov[lane * 9 + j], c9[j], acc);
    float fcov = fmaxf(acc, 0.f);

    // --- feature max-pool: lane = input channel c of 64, coalesced gather ---
    float fm = -1e30f;
#pragma unroll
    for (int kk = 0; kk < KNN; ++kk) {
        int ni = sknn[kk];
        fm = fmaxf(fm, fT[((size_t)b * NPTS + ni) * CIN + lane]);
    }

    float* dst = fcat + (size_t)q * (CIN + CCOV);
    dst[lane]       = fm;
    dst[CIN + lane] = fcov;
}

// ---------------------------------------------------------------------------
// K3: out[b,co,m] = relu(b_f[co] + sum_ci W_f[co,ci] * f_cat[b,m,ci])
// Block: one (b, 32-m tile); 256 threads: m = tid&31, 16 co per thread.
// ---------------------------------------------------------------------------
__global__ void k_mlp(const float* __restrict__ fcat, const float* __restrict__ Wf,
                      const float* __restrict__ bf, float* __restrict__ out) {
    __shared__ float tile[32][132];   // [m][ci], padded, rows 16B-aligned
    int b  = blockIdx.y;
    int m0 = blockIdx.x * 32;
    int tid = threadIdx.x;
    const float4* src = (const float4*)(fcat + ((size_t)b * MPTS + m0) * 128);
#pragma unroll
    for (int r = 0; r < 4; ++r) {
        int e  = tid + 256 * r;       // float4 index in [32][128]
        int mm = e >> 5;
        int c4 = e & 31;
        float4 v = src[e];
        *(float4*)&tile[mm][c4 * 4] = v;
    }
    __syncthreads();

    int m   = tid & 31;
    int cog = tid >> 5;               // 8 groups of 16 co
    float acc[16];
#pragma unroll
    for (int j = 0; j < 16; ++j) acc[j] = bf[cog * 16 + j];

    for (int c4 = 0; c4 < 32; ++c4) {
        float4 fv = *(const float4*)&tile[m][c4 * 4];
#pragma unroll
        for (int j = 0; j < 16; ++j) {
            int co = cog * 16 + j;
            float4 wv = ((const float4*)(Wf + (size_t)co * 128))[c4];
            acc[j] = fmaf(wv.x, fv.x, acc[j]);
            acc[j] = fmaf(wv.y, fv.y, acc[j]);
            acc[j] = fmaf(wv.z, fv.z, acc[j]);
            acc[j] = fmaf(wv.w, fv.w, acc[j]);
        }
    }
#pragma unroll
    for (int j = 0; j < 16; ++j) {
        int co = cog * 16 + j;
        out[((size_t)b * COUT + co) * MPTS + m0 + m] = fmaxf(acc[j], 0.f);
    }
}

// ---------------------------------------------------------------------------
extern "C" void kernel_launch(void* const* d_in, const int* in_sizes, int n_in,
                              void* d_out, int out_size, void* d_ws, size_t ws_size,
                              hipStream_t stream) {
    const float* f    = (const float*)d_in[0];   // [8,64,4096]
    const float* xyz  = (const float*)d_in[1];   // [8,4096,3]
    const float* Wcov = (const float*)d_in[2];   // [64,9]
    const float* bcov = (const float*)d_in[3];   // [64]
    const float* Wf   = (const float*)d_in[4];   // [128,128]
    const float* bf   = (const float*)d_in[5];   // [128]

    float* out     = (float*)d_out;                      // [8,128,1024]
    float* xyz_new = out + (size_t)BATCH * COUT * MPTS;  // [8,1024,3]

    float* fT   = (float*)d_ws;                          // [8,4096,64]  8 MB
    float* fcat = fT + (size_t)BATCH * NPTS * CIN;       // [8*1024,128] 4 MB

    k_transpose<<<dim3(64, BATCH), 256, 0, stream>>>(f, fT);
    k_fps<<<BATCH, 1024, 0, stream>>>(xyz, xyz_new);
    k_knn<<<BATCH * MPTS, 64, 0, stream>>>(xyz, xyz_new, fT, Wcov, bcov, fcat);
    k_mlp<<<dim3(MPTS / 32, BATCH), 256, 0, stream>>>(fcat, Wf, bf, out);
}

// Round 7
// 1148.461 us; speedup vs baseline: 1.3454x; 1.3454x over previous
//
#include <hip/hip_runtime.h>
#include <hip/hip_bf16.h>
#include <stdint.h>

// Problem constants
#define BATCH 8
#define NPTS  4096
#define CIN   64
#define MPTS  1024
#define KNN   32
#define CCOV  64
#define COUT  128
#define CCAP  1024   // knn candidate buffer cap

typedef unsigned long long u64;
typedef unsigned int u32;

// ---------------------------------------------------------------------------
// K0: transpose f [B, 64, 4096] -> fT [B, 4096, 64] for coalesced gathers
// ---------------------------------------------------------------------------
__global__ void k_transpose(const float* __restrict__ f, float* __restrict__ fT) {
    __shared__ float tile[64][65];
    int b  = blockIdx.y;
    int n0 = blockIdx.x * 64;
    int tx = threadIdx.x & 63;
    int ty = threadIdx.x >> 6;   // 0..3
#pragma unroll
    for (int r = 0; r < 16; ++r) {
        int c = r * 4 + ty;
        tile[c][tx] = f[((size_t)b * CIN + c) * NPTS + n0 + tx];
    }
    __syncthreads();
#pragma unroll
    for (int r = 0; r < 16; ++r) {
        int n = r * 4 + ty;
        fT[((size_t)b * NPTS + n0 + n) * CIN + tx] = tile[tx][n];
    }
}

// ---------------------------------------------------------------------------
// DPP full-wave max reduce for f32 (gfx9-family: row_shr + bcast15/31).
// dpp_ctrl must be a compile-time constant -> template parameter.
// bound_ctrl=false: invalid source lanes keep old value (idempotent for max).
// Result broadcast via readlane 63.
// ---------------------------------------------------------------------------
template <int CTRL>
__device__ __forceinline__ float dpp_step_max(float x) {
    int xi = __float_as_int(x);
    int yi = __builtin_amdgcn_update_dpp(xi, xi, CTRL, 0xF, 0xF, false);
    return fmaxf(x, __int_as_float(yi));
}
__device__ __forceinline__ float wave_max_dpp(float x) {
    x = dpp_step_max<0x111>(x);  // row_shr:1
    x = dpp_step_max<0x112>(x);  // row_shr:2
    x = dpp_step_max<0x114>(x);  // row_shr:4
    x = dpp_step_max<0x118>(x);  // row_shr:8
    x = dpp_step_max<0x142>(x);  // row_bcast:15
    x = dpp_step_max<0x143>(x);  // row_bcast:31
    return __int_as_float(__builtin_amdgcn_readlane(__float_as_int(x), 63));
}

// ---------------------------------------------------------------------------
// K1: farthest point sampling, f32 main loop + exact-f64 rare path.
// 512 threads (8 waves) per batch, 8 points/thread in registers.
// Per step: f32 running-min update (fma chain), DPP wave max, 8-slot LDS
// combine; candidate set = dists within 4e-6 rel of max (f32 error vs f64
// is <= ~6e-7 rel, margin > 2x bound). If exactly 1 candidate -> it IS the
// exact f64 argmax, no f64 work. Else: recompute candidates' exact f64
// running min over selected centroids (sel[] in LDS), key =
// (d64bits & ~0xFFF) | (~idx & 0xFFF) max-reduced -> max dist, first index
// (np.argmax semantics).
// ---------------------------------------------------------------------------
__launch_bounds__(512, 1)
__global__ void k_fps(const float* __restrict__ xyz, float* __restrict__ xyz_new) {
    __shared__ float sx[NPTS], sy[NPTS], sz[NPTS];
    __shared__ int   sel[MPTS];
    __shared__ __align__(16) float wmax[2][8];
    __shared__ u64 wkey[2], wkey2[2];
    __shared__ int wcnt[2];
    __shared__ int cand[2][32];

    int b    = blockIdx.x;
    int tid  = threadIdx.x;
    int lane = tid & 63, wid = tid >> 6;
    const float* xb = xyz + (size_t)b * NPTS * 3;
    float px[8], py[8], pz[8], dist[8];
#pragma unroll
    for (int j = 0; j < 8; ++j) {
        int i = tid + 512 * j;
        px[j] = xb[i * 3 + 0];
        py[j] = xb[i * 3 + 1];
        pz[j] = xb[i * 3 + 2];
        sx[i] = px[j]; sy[i] = py[j]; sz[i] = pz[j];
        dist[j] = 1e30f;
    }
    __syncthreads();

    int far = 0;
    float* xout = xyz_new + (size_t)b * MPTS * 3;

    for (int m = 0; m < MPTS; ++m) {
        int p = m & 1;
        float fx = sx[far], fy = sy[far], fz = sz[far];
        if (tid == 0) {   // record centroid BEFORE update (scan semantics)
            xout[m * 3 + 0] = fx;
            xout[m * 3 + 1] = fy;
            xout[m * 3 + 2] = fz;
            sel[m] = far;
            wcnt[p] = 0; wkey[p] = 0; wkey2[p] = 0;   // parity-safe reset
        }
        float lmax = 0.f;
#pragma unroll
        for (int j = 0; j < 8; ++j) {
            float dx = px[j] - fx, dy = py[j] - fy, dz = pz[j] - fz;
            float d  = fmaf(dx, dx, fmaf(dy, dy, dz * dz));
            dist[j] = fminf(dist[j], d);
            lmax = fmaxf(lmax, dist[j]);
        }
        float wm = wave_max_dpp(lmax);
        if (lane == 0) wmax[p][wid] = wm;
        __syncthreads();

        float4 a4 = *(const float4*)&wmax[p][0];
        float4 b4 = *(const float4*)&wmax[p][4];
        float gmax = fmaxf(fmaxf(fmaxf(a4.x, a4.y), fmaxf(a4.z, a4.w)),
                           fmaxf(fmaxf(b4.x, b4.y), fmaxf(b4.z, b4.w)));
        float thresh = gmax * (1.0f - 4e-6f);

        bool any = false;
#pragma unroll
        for (int j = 0; j < 8; ++j) any |= (dist[j] >= thresh);
        if (any) {
#pragma unroll
            for (int j = 0; j < 8; ++j) {
                if (dist[j] >= thresh) {
                    int i = tid + 512 * j;
                    int pos = atomicAdd(&wcnt[p], 1);
                    if (pos < 32) cand[p][pos] = i;
                    atomicMax(&wkey[p],
                              ((u64)__float_as_uint(dist[j]) << 32) | (u32)(~(u32)i));
                }
            }
        }
        __syncthreads();

        int nc = wcnt[p];
        if (nc == 1) {
            far = (int)(~(u32)wkey[p]);
        } else {
            // rare exact path: f64 running min for each candidate
            int nc2 = nc < 32 ? nc : 32;
            for (int c = wid; c < nc2; c += 8) {
                int i = cand[p][c];
                double cx = (double)sx[i], cy = (double)sy[i], cz = (double)sz[i];
                double dmin = 1e10;
                for (int t = lane; t <= m; t += 64) {
                    int s = sel[t];
                    double ddx = __dsub_rn(cx, (double)sx[s]);
                    double ddy = __dsub_rn(cy, (double)sy[s]);
                    double ddz = __dsub_rn(cz, (double)sz[s]);
                    double d64 = __dadd_rn(__dadd_rn(__dmul_rn(ddx, ddx),
                                                     __dmul_rn(ddy, ddy)),
                                           __dmul_rn(ddz, ddz));
                    dmin = fmin(dmin, d64);
                }
#pragma unroll
                for (int off = 32; off; off >>= 1)
                    dmin = fmin(dmin, __shfl_xor(dmin, off));
                if (lane == 0)
                    atomicMax(&wkey2[p],
                              ((u64)__double_as_longlong(dmin) & ~0xFFFull) |
                              (u64)((~(u32)i) & 0xFFFu));
            }
            __syncthreads();   // uniform: nc same for all threads
            far = (int)((~(u32)wkey2[p]) & 0xFFFu);
        }
    }
}

// ---------------------------------------------------------------------------
// K2: per-query (one wave) 32-NN, f32-filtered + exact-f64 on candidates.
// cutoff c0 = wave_max(per-lane min d32) -> every lane has >=1 point <= c0
// (so n0 >= 64), and cut = c0*(1+4e-6) provably contains the true f64
// top-32 (needs > 2x the ~6e-7 rel f32-vs-f64 error bound). Exact f64 keys
// (d64bits&~0xFFF)|idx for candidates only; 32x thr-filtered min-extraction
// (unique keys). Fallback (n0 > CCAP, ~never): per-round full f64 scan,
// identical semantics. Then max-pool + covariance + mlp_cov -> f_cat.
// ---------------------------------------------------------------------------
__launch_bounds__(64)
__global__ void k_knn(const float* __restrict__ xyz, const float* __restrict__ xyz_new,
                      const float* __restrict__ fT, const float* __restrict__ Wcov,
                      const float* __restrict__ bcov, float* __restrict__ fcat) {
    __shared__ u32 cidx[CCAP];
    __shared__ u64 kbuf[CCAP];
    __shared__ int sknn[KNN];
    __shared__ int cnt;

    int q = blockIdx.x;            // 0..8191
    int b = q >> 10, m = q & 1023;
    int lane = threadIdx.x;
    const float* xb = xyz + (size_t)b * NPTS * 3;

    float cxf = xyz_new[((size_t)b * MPTS + m) * 3 + 0];
    float cyf = xyz_new[((size_t)b * MPTS + m) * 3 + 1];
    float czf = xyz_new[((size_t)b * MPTS + m) * 3 + 2];
    double cx = (double)cxf, cy = (double)cyf, cz = (double)czf;

    if (lane == 0) cnt = 0;

    // f32 distance pass, per-lane min
    float d[64];
    float lmin = 1e30f;
#pragma unroll
    for (int t = 0; t < 64; ++t) {
        int i = lane + 64 * t;
        float dx = cxf - xb[i * 3 + 0];
        float dy = cyf - xb[i * 3 + 1];
        float dz = czf - xb[i * 3 + 2];
        d[t] = fmaf(dx, dx, fmaf(dy, dy, dz * dz));
        lmin = fminf(lmin, d[t]);
    }
    float c0  = wave_max_dpp(lmin);
    float cut = c0 * (1.0f + 4e-6f);
    __syncthreads();   // cnt reset visible

    // compact candidate indices
#pragma unroll
    for (int t = 0; t < 64; ++t) {
        if (d[t] <= cut) {
            int pos = atomicAdd(&cnt, 1);
            if (pos < CCAP) cidx[pos] = (u32)(lane + 64 * t);
        }
    }
    __syncthreads();
    int n0 = cnt;

    if (n0 <= CCAP) {
        // exact f64 keys for candidates (each lane owns c = lane + 64j)
        for (int c = lane; c < n0; c += 64) {
            int i = (int)cidx[c];
            double dx = __dsub_rn(cx, (double)xb[i * 3 + 0]);
            double dy = __dsub_rn(cy, (double)xb[i * 3 + 1]);
            double dz = __dsub_rn(cz, (double)xb[i * 3 + 2]);
            double d2 = __dadd_rn(__dadd_rn(__dmul_rn(dx, dx), __dmul_rn(dy, dy)),
                                  __dmul_rn(dz, dz));
            kbuf[c] = ((u64)__double_as_longlong(d2) & ~0xFFFull) | (u64)i;
        }
        // 32x min-extraction over own LDS keys (same-lane RAW, no barrier)
        u64 thr = 0;
        for (int it = 0; it < KNN; ++it) {
            u64 best = ~0ull;
            for (int c = lane; c < n0; c += 64) {
                u64 v = kbuf[c];
                if (v >= thr && v < best) best = v;
            }
#pragma unroll
            for (int off = 1; off < 64; off <<= 1) {
                u64 o = __shfl_xor(best, off);
                if (o < best) best = o;
            }
            if (lane == 0) sknn[it] = (int)(best & 0xFFFull);
            thr = best + 1;
        }
    } else {
        // fallback: full f64 scan per extraction round (correctness insurance)
        u64 thr = 0;
        for (int it = 0; it < KNN; ++it) {
            u64 best = ~0ull;
#pragma unroll 4
            for (int t = 0; t < 64; ++t) {
                int i = lane + 64 * t;
                double dx = __dsub_rn(cx, (double)xb[i * 3 + 0]);
                double dy = __dsub_rn(cy, (double)xb[i * 3 + 1]);
                double dz = __dsub_rn(cz, (double)xb[i * 3 + 2]);
                double d2 = __dadd_rn(__dadd_rn(__dmul_rn(dx, dx), __dmul_rn(dy, dy)),
                                      __dmul_rn(dz, dz));
                u64 v = ((u64)__double_as_longlong(d2) & ~0xFFFull) | (u64)i;
                if (v >= thr && v < best) best = v;
            }
#pragma unroll
            for (int off = 1; off < 64; off <<= 1) {
                u64 o = __shfl_xor(best, off);
                if (o < best) best = o;
            }
            if (lane == 0) sknn[it] = (int)(best & 0xFFFull);
            thr = best + 1;
        }
    }
    __syncthreads();

    // --- covariance of neighbor coords (each neighbor counted twice: /64) ---
    int nk = sknn[lane & 31];
    float nx = xb[nk * 3 + 0], ny = xb[nk * 3 + 1], nz = xb[nk * 3 + 2];
    float sxs = nx, sys = ny, szs = nz;
#pragma unroll
    for (int off = 1; off < 64; off <<= 1) {
        sxs += __shfl_xor(sxs, off);
        sys += __shfl_xor(sys, off);
        szs += __shfl_xor(szs, off);
    }
    float mx = sxs * (1.f / 64.f), my = sys * (1.f / 64.f), mz = szs * (1.f / 64.f);
    float ux = nx - mx, uy = ny - my, uz = nz - mz;
    float pxx = ux * ux, pxy = ux * uy, pxz = ux * uz;
    float pyy = uy * uy, pyz = uy * uz, pzz = uz * uz;
#pragma unroll
    for (int off = 1; off < 64; off <<= 1) {
        pxx += __shfl_xor(pxx, off);
        pxy += __shfl_xor(pxy, off);
        pxz += __shfl_xor(pxz, off);
        pyy += __shfl_xor(pyy, off);
        pyz += __shfl_xor(pyz, off);
        pzz += __shfl_xor(pzz, off);
    }
    const float inv = 1.f / 64.f;   // = (sum*2)/(2*K), K=32
    float c9[9];
    c9[0] = pxx * inv; c9[1] = pxy * inv; c9[2] = pxz * inv;
    c9[3] = pxy * inv; c9[4] = pyy * inv; c9[5] = pyz * inv;
    c9[6] = pxz * inv; c9[7] = pyz * inv; c9[8] = pzz * inv;

    // --- mlp_cov: lane = out channel c of 64 ---
    float acc = bcov[lane];
#pragma unroll
    for (int j = 0; j < 9; ++j) acc = fmaf(Wcov[lane * 9 + j], c9[j], acc);
    float fcov = fmaxf(acc, 0.f);

    // --- feature max-pool: lane = input channel c of 64, coalesced gather ---
    float fm = -1e30f;
#pragma unroll
    for (int kk = 0; kk < KNN; ++kk) {
        int ni = sknn[kk];
        fm = fmaxf(fm, fT[((size_t)b * NPTS + ni) * CIN + lane]);
    }

    float* dst = fcat + (size_t)q * (CIN + CCOV);
    dst[lane]       = fm;
    dst[CIN + lane] = fcov;
}

// ---------------------------------------------------------------------------
// K3: out[b,co,m] = relu(b_f[co] + sum_ci W_f[co,ci] * f_cat[b,m,ci])
// Block: one (b, 32-m tile); 256 threads: m = tid&31, 16 co per thread.
// ---------------------------------------------------------------------------
__global__ void k_mlp(const float* __restrict__ fcat, const float* __restrict__ Wf,
                      const float* __restrict__ bf, float* __restrict__ out) {
    __shared__ float tile[32][132];   // [m][ci], padded, rows 16B-aligned
    int b  = blockIdx.y;
    int m0 = blockIdx.x * 32;
    int tid = threadIdx.x;
    const float4* src = (const float4*)(fcat + ((size_t)b * MPTS + m0) * 128);
#pragma unroll
    for (int r = 0; r < 4; ++r) {
        int e  = tid + 256 * r;       // float4 index in [32][128]
        int mm = e >> 5;
        int c4 = e & 31;
        float4 v = src[e];
        *(float4*)&tile[mm][c4 * 4] = v;
    }
    __syncthreads();

    int m   = tid & 31;
    int cog = tid >> 5;               // 8 groups of 16 co
    float acc[16];
#pragma unroll
    for (int j = 0; j < 16; ++j) acc[j] = bf[cog * 16 + j];

    for (int c4 = 0; c4 < 32; ++c4) {
        float4 fv = *(const float4*)&tile[m][c4 * 4];
#pragma unroll
        for (int j = 0; j < 16; ++j) {
            int co = cog * 16 + j;
            float4 wv = ((const float4*)(Wf + (size_t)co * 128))[c4];
            acc[j] = fmaf(wv.x, fv.x, acc[j]);
            acc[j] = fmaf(wv.y, fv.y, acc[j]);
            acc[j] = fmaf(wv.z, fv.z, acc[j]);
            acc[j] = fmaf(wv.w, fv.w, acc[j]);
        }
    }
#pragma unroll
    for (int j = 0; j < 16; ++j) {
        int co = cog * 16 + j;
        out[((size_t)b * COUT + co) * MPTS + m0 + m] = fmaxf(acc[j], 0.f);
    }
}

// ---------------------------------------------------------------------------
extern "C" void kernel_launch(void* const* d_in, const int* in_sizes, int n_in,
                              void* d_out, int out_size, void* d_ws, size_t ws_size,
                              hipStream_t stream) {
    const float* f    = (const float*)d_in[0];   // [8,64,4096]
    const float* xyz  = (const float*)d_in[1];   // [8,4096,3]
    const float* Wcov = (const float*)d_in[2];   // [64,9]
    const float* bcov = (const float*)d_in[3];   // [64]
    const float* Wf   = (const float*)d_in[4];   // [128,128]
    const float* bf   = (const float*)d_in[5];   // [128]

    float* out     = (float*)d_out;                      // [8,128,1024]
    float* xyz_new = out + (size_t)BATCH * COUT * MPTS;  // [8,1024,3]

    float* fT   = (float*)d_ws;                          // [8,4096,64]  8 MB
    float* fcat = fT + (size_t)BATCH * NPTS * CIN;       // [8*1024,128] 4 MB

    k_transpose<<<dim3(64, BATCH), 256, 0, stream>>>(f, fT);
    k_fps<<<BATCH, 512, 0, stream>>>(xyz, xyz_new);
    k_knn<<<BATCH * MPTS, 64, 0, stream>>>(xyz, xyz_new, fT, Wcov, bcov, fcat);
    k_mlp<<<dim3(MPTS / 32, BATCH), 256, 0, stream>>>(fcat, Wf, bf, out);
}